// Round 17
// baseline (125.183 us; speedup 1.0000x reference)
//
#include <hip/hip_runtime.h>
#include <math.h>

#define D_MODEL 768
#define NHEAD  12
#define HDIM   64
#define SEQ    1024
#define BATCH  8
#define MTOT   (BATCH*SEQ)   // 8192
#define QKV_N  2304          // gemm output columns (Q|K|V)
#define QK_LD  1536          // Q|K buffer row stride (V lives in Vt)
#define NBH    (BATCH*NHEAD) // 96

typedef _Float16 f16;
typedef __attribute__((ext_vector_type(2))) __fp16 fp16x2;
typedef __attribute__((ext_vector_type(4))) _Float16 f16x4;
typedef __attribute__((ext_vector_type(8))) _Float16 f16x8;
typedef __attribute__((ext_vector_type(4))) float f32x4;
typedef __attribute__((ext_vector_type(16))) float f32x16;

union PFrag { unsigned u[4]; f16x8 v; };
union PackW { fp16x2 h; unsigned u; };

__device__ inline void gload_lds16(const void* g, void* l) {
    __builtin_amdgcn_global_load_lds(
        (const __attribute__((address_space(1))) void*)g,
        (__attribute__((address_space(3))) void*)l, 16, 0, 0);
}

// ---------------------------------------------------------------------------
// Merged prepass: blocks [0,3072) = x fp32->f16 (+bias concat in blocks 0..8);
// blocks [3072,3648) = four W transposes (idx selects matrix + tile).
// ---------------------------------------------------------------------------
__global__ __launch_bounds__(256) void prepass(
    const float* __restrict__ x, f16* __restrict__ xh, int n8,
    const float* __restrict__ bq, const float* __restrict__ bk,
    const float* __restrict__ bv, float* __restrict__ bqkv,
    const float* __restrict__ Wq, const float* __restrict__ Wk,
    const float* __restrict__ Wv, const float* __restrict__ Wo,
    f16* __restrict__ Wqkv_t, f16* __restrict__ Wo_t)
{
    __shared__ f16 tile[64][72];
    const int t = threadIdx.x;

    if (blockIdx.x < 3072) {
        const int i = blockIdx.x * 256 + t;
        if (i < n8) {
            const float4 a = *(const float4*)(x + (size_t)i * 8);
            const float4 b = *(const float4*)(x + (size_t)i * 8 + 4);
            f16x8 v;
            v[0] = (f16)a.x; v[1] = (f16)a.y; v[2] = (f16)a.z; v[3] = (f16)a.w;
            v[4] = (f16)b.x; v[5] = (f16)b.y; v[6] = (f16)b.z; v[7] = (f16)b.w;
            *(f16x8*)(xh + (size_t)i * 8) = v;
        }
        if (i < QKV_N)
            bqkv[i] = (i < 768) ? bq[i] : (i < 1536) ? bk[i - 768] : bv[i - 1536];
    } else {
        const int idx = blockIdx.x - 3072;
        const int z   = idx / 144;
        const int rem = idx % 144;
        const int k0  = (rem / 12) * 64;
        const int n0  = (rem % 12) * 64;
        const float* src = (z == 0) ? Wq : (z == 1) ? Wk : (z == 2) ? Wv : Wo;
        f16* dst = (z < 3) ? (Wqkv_t + (size_t)z * 768 * 768) : Wo_t;

        {
            const int r  = t >> 4;
            const int c4 = (t & 15) * 4;
            #pragma unroll
            for (int u = 0; u < 4; ++u) {
                const int row = r + u * 16;
                const float4 a = *(const float4*)&src[(size_t)(k0 + row) * 768 + n0 + c4];
                tile[row][c4 + 0] = (f16)a.x;
                tile[row][c4 + 1] = (f16)a.y;
                tile[row][c4 + 2] = (f16)a.z;
                tile[row][c4 + 3] = (f16)a.w;
            }
        }
        __syncthreads();
        {
            const int rn = t >> 3;
            const int ck = (t & 7) * 8;
            #pragma unroll
            for (int u = 0; u < 2; ++u) {
                const int n = rn + u * 32;
                f16x8 v;
                #pragma unroll
                for (int q = 0; q < 8; ++q) v[q] = tile[ck + q][n];
                *(f16x8*)&dst[(size_t)(n0 + n) * 768 + k0 + ck] = v;
            }
        }
    }
}

// ---------------------------------------------------------------------------
// C[M][N] = A[M][K]f16 @ Bt[N][K]f16^T + bias.  128xBN tile, 4 waves,
// 64x(BN/2)/wave, BK=64. global_load_lds(16B) staging; 8-slot add-rotate
// k-chunk swizzle. 1D grid, XCD-contiguous chunk mapping.
// BN=128 for QKV (grid 1152); BN=64 for Wo (grid 768 = exactly 3/CU).
// SPLITV: cols >= 1536 (V) scatter to Vt[bh][d][seq] (transposed f16x4).
// ---------------------------------------------------------------------------
template<typename OUT_T, bool SPLITV, int BN>
__global__ __launch_bounds__(256) void gemm_f16_tn(
    const f16* __restrict__ A, const f16* __restrict__ Bt,
    const float* __restrict__ bias, OUT_T* __restrict__ C,
    f16* __restrict__ Vt,
    int M, int N, int K, int nb, int ldc)
{
    constexpr int NJ = BN / 32;          // j-tiles per wave (4 or 2)
    __shared__ f16 As[128 * 64];
    __shared__ f16 Bs[BN * 64];

    const int t    = threadIdx.x;
    const int l15  = (t & 63) & 15;
    const int lg   = (t & 63) >> 4;
    const int w    = t >> 6;
    const int wrow = (w >> 1) * 64;
    const int wcol = (w & 1) * (BN / 2);

    const int orig = blockIdx.x;
    const int cpx  = gridDim.x >> 3;
    const int nid  = (orig & 7) * cpx + (orig >> 3);
    const int row0 = (nid / nb) * 128;
    const int col0 = (nid % nb) * BN;

    int src_row[4], src_koff[4], lds_off[4];
    #pragma unroll
    for (int i = 0; i < 4; ++i) {
        const int c = t + 256 * i;
        const int r = c >> 3;
        src_row[i]  = r;
        src_koff[i] = ((((c & 7) - (r >> 1)) & 7)) * 8;
        lds_off[i]  = c * 16;
    }

    int a_off[4][2], b_off[NJ][2];
    #pragma unroll
    for (int i = 0; i < 4; ++i) {
        const int ra = wrow + i * 16 + l15;
        #pragma unroll
        for (int s = 0; s < 2; ++s)
            a_off[i][s] = ra * 128 + (((s * 4 + lg + (ra >> 1)) & 7) * 16);
    }
    #pragma unroll
    for (int j = 0; j < NJ; ++j) {
        const int rb = wcol + j * 16 + l15;
        #pragma unroll
        for (int s = 0; s < 2; ++s)
            b_off[j][s] = rb * 128 + (((s * 4 + lg + (rb >> 1)) & 7) * 16);
    }

    f32x4 acc[4][NJ];
    #pragma unroll
    for (int i = 0; i < 4; ++i)
        #pragma unroll
        for (int j = 0; j < NJ; ++j)
            acc[i][j] = (f32x4){0.f, 0.f, 0.f, 0.f};

    const f16* Abase = A  + (size_t)row0 * K;
    const f16* Bbase = Bt + (size_t)col0 * K;

    for (int k0 = 0; k0 < K; k0 += 64) {
        #pragma unroll
        for (int i = 0; i < 4; ++i)
            gload_lds16(Abase + (size_t)src_row[i] * K + k0 + src_koff[i],
                        (char*)As + lds_off[i]);
        #pragma unroll
        for (int i = 0; i < BN / 32; ++i)
            gload_lds16(Bbase + (size_t)src_row[i] * K + k0 + src_koff[i],
                        (char*)Bs + lds_off[i]);
        __syncthreads();

        #pragma unroll
        for (int s = 0; s < 2; ++s) {
            f16x8 af[4], bf[NJ];
            #pragma unroll
            for (int i = 0; i < 4; ++i)
                af[i] = *(const f16x8*)((const char*)As + a_off[i][s]);
            #pragma unroll
            for (int j = 0; j < NJ; ++j)
                bf[j] = *(const f16x8*)((const char*)Bs + b_off[j][s]);
            #pragma unroll
            for (int i = 0; i < 4; ++i)
                #pragma unroll
                for (int j = 0; j < NJ; ++j)
                    acc[i][j] = __builtin_amdgcn_mfma_f32_16x16x32_f16(
                        af[i], bf[j], acc[i][j], 0, 0, 0);
        }
        __syncthreads();
    }

    #pragma unroll
    for (int j = 0; j < NJ; ++j) {
        const int col = col0 + wcol + j * 16 + l15;
        const float bj = bias[col];
        if (!SPLITV || col < 1536) {
            #pragma unroll
            for (int i = 0; i < 4; ++i) {
                const int row = row0 + wrow + i * 16 + lg * 4;
                #pragma unroll
                for (int q = 0; q < 4; ++q)
                    C[(size_t)(row + q) * ldc + col] = (OUT_T)(acc[i][j][q] + bj);
            }
        } else if (SPLITV) {
            const int h2 = (col - 1536) >> 6;
            const int d  = (col - 1536) & 63;
            #pragma unroll
            for (int i = 0; i < 4; ++i) {
                const int row = row0 + wrow + i * 16 + lg * 4;
                const int bb  = row >> 10;
                const int tok = row & 1023;
                f16x4 v4;
                #pragma unroll
                for (int q = 0; q < 4; ++q) v4[q] = (f16)(acc[i][j][q] + bj);
                *(f16x4*)(Vt + (((size_t)(bb * NHEAD + h2)) * 64 + d) * SEQ + tok) = v4;
            }
        }
    }
}

// ---------------------------------------------------------------------------
// Flash attention, f16, 32x32x16 MFMA, fixed-shift softmax, DMA staging
// (round-15/16 proven), now KV-SPLIT ACROSS BLOCKS (flash-decoding style):
// grid = 1536 = 96 bh x 8 qb x 2 halves; each block does 8 KV tiles and
// writes UNNORMALIZED f16 ctx partial + per-q lsum. Fixed-shift softmax
// makes partials exactly additive (no max bookkeeping) -> trivial merge.
// 5 blocks/CU resident (LDS 32KB) -> 5 waves/SIMD vs 3 before.
// ---------------------------------------------------------------------------
#define QMAP(r, hh) (((r) & 3) + 8 * ((r) >> 2) + 4 * (hh))

__global__ __launch_bounds__(256, 3) void attn_f16(
    const f16* __restrict__ QK, const f16* __restrict__ Vt,
    f16* __restrict__ PA, f16* __restrict__ PB, float* __restrict__ L)
{
    __shared__ f16 KsB[2][64 * 64];   // [k][d], swizzled
    __shared__ f16 VtB[2][64 * 64];   // [d][k], swizzled

    const int t   = threadIdx.x;
    const int w   = t >> 6;
    const int l   = t & 63;
    const int l31 = l & 31;
    const int h   = l >> 5;
    const int sl  = (l & 7) << 4;     // read XOR key (row&7)

    const int orig = blockIdx.x;                 // 0..1535
    const int s    = (orig & 7) * 192 + (orig >> 3);
    const int bh   = s >> 4;                     // 0..95
    const int qb   = (s >> 1) & 7;               // 0..7
    const int half = s & 1;                      // kv half
    const int b  = bh / NHEAD;
    const int hd = bh % NHEAD;
    const int q0 = qb * 128;

    const size_t rowbase = (size_t)b * SEQ;
    const int qcol = hd * HDIM;

    // ---- hoist Q fragments (B-operand: col=l31=q, k=h*8+j per 16-d chunk) --
    const f16 hsc = (f16)(0.125f * 1.4426950408889634f);
    f16x8 qf[4];
    #pragma unroll
    for (int dc = 0; dc < 4; ++dc) {
        f16x8 v = *(const f16x8*)(QK
            + (rowbase + q0 + w * 32 + l31) * QK_LD
            + qcol + dc * 16 + h * 8);
        #pragma unroll
        for (int j = 0; j < 8; ++j) v[j] *= hsc;
        qf[dc] = v;
    }

    f32x16 ctx[2];
    #pragma unroll
    for (int dt = 0; dt < 2; ++dt)
        #pragma unroll
        for (int r = 0; r < 16; ++r) ctx[dt][r] = 0.f;
    float lsum = 0.f;   // per-lane partial P-sum (q = l31)

    // ---- staging sources (pre-swizzled), offset to this block's kv half ----
    const int rsub   = l >> 3;
    const int schunk = (l & 7) ^ rsub;
    const size_t kstep = (size_t)64 * QK_LD;
    const f16* ksrc = QK + (rowbase + w * 16 + rsub) * QK_LD
                         + 768 + qcol + schunk * 8 + (size_t)(half * 8) * kstep;
    const f16* vsrc = Vt + (((size_t)bh * 64) + w * 16 + rsub) * SEQ
                         + schunk * 8 + half * 8 * 64;
    const int woff = w * 2048;

    // ---- prologue: DMA tile 0 into buf 0 ----
    gload_lds16(ksrc,             (char*)KsB[0] + woff);
    gload_lds16(ksrc + 8 * QK_LD, (char*)KsB[0] + woff + 1024);
    gload_lds16(vsrc,             (char*)VtB[0] + woff);
    gload_lds16(vsrc + 8 * SEQ,   (char*)VtB[0] + woff + 1024);
    __syncthreads();

    for (int kt = 0; kt < 8; ++kt) {
        const int p = kt & 1;

        if (kt < 7) {
            const f16* ks = ksrc + (size_t)(kt + 1) * kstep;
            const f16* vs = vsrc + (kt + 1) * 64;
            gload_lds16(ks,             (char*)KsB[p ^ 1] + woff);
            gload_lds16(ks + 8 * QK_LD, (char*)KsB[p ^ 1] + woff + 1024);
            gload_lds16(vs,             (char*)VtB[p ^ 1] + woff);
            gload_lds16(vs + 8 * SEQ,   (char*)VtB[p ^ 1] + woff + 1024);
        }

        const char* Kp = (const char*)KsB[p];
        const char* Vp = (const char*)VtB[p];

        // ---- S^T = K @ Q^T ----
        f32x16 sacc[2];
        __builtin_amdgcn_s_setprio(1);
        #pragma unroll
        for (int kk = 0; kk < 2; ++kk) {
            f32x16 a;
            #pragma unroll
            for (int r = 0; r < 16; ++r) a[r] = 0.f;
            #pragma unroll
            for (int dc = 0; dc < 4; ++dc) {
                const f16x8 ka = *(const f16x8*)(Kp + (kk * 32 + l31) * 128
                                                    + ((dc * 32 + h * 16) ^ sl));
                a = __builtin_amdgcn_mfma_f32_32x32x16_f16(ka, qf[dc], a, 0, 0, 0);
            }
            sacc[kk] = a;
        }
        __builtin_amdgcn_s_setprio(0);

        // ---- fixed-shift softmax: P = exp2(s), 4-way tree partial sum ----
        {
            float ps0 = 0.f, ps1 = 0.f, ps2 = 0.f, ps3 = 0.f;
            #pragma unroll
            for (int kk = 0; kk < 2; ++kk)
                #pragma unroll
                for (int r = 0; r < 16; r += 4) {
                    const float e0 = exp2f(sacc[kk][r + 0]);
                    const float e1 = exp2f(sacc[kk][r + 1]);
                    const float e2 = exp2f(sacc[kk][r + 2]);
                    const float e3 = exp2f(sacc[kk][r + 3]);
                    sacc[kk][r + 0] = e0; ps0 += e0;
                    sacc[kk][r + 1] = e1; ps1 += e1;
                    sacc[kk][r + 2] = e2; ps2 += e2;
                    sacc[kk][r + 3] = e3; ps3 += e3;
                }
            lsum += (ps0 + ps1) + (ps2 + ps3);
        }

        // ---- pack P to f16 dwords, redistribute across half-waves ----
        unsigned paw[4][4];
        #pragma unroll
        for (int kk = 0; kk < 2; ++kk) {
            unsigned dw[8];
            #pragma unroll
            for (int i = 0; i < 8; ++i) {
                PackW u;
                u.h = __builtin_amdgcn_cvt_pkrtz(sacc[kk][2 * i], sacc[kk][2 * i + 1]);
                dw[i] = u.u;
            }
            const unsigned t0 = (unsigned)__shfl_xor((int)(h ? dw[0] : dw[2]), 32);
            const unsigned t1 = (unsigned)__shfl_xor((int)(h ? dw[1] : dw[3]), 32);
            const unsigned t2 = (unsigned)__shfl_xor((int)(h ? dw[4] : dw[6]), 32);
            const unsigned t3 = (unsigned)__shfl_xor((int)(h ? dw[5] : dw[7]), 32);
            paw[2 * kk][0]     = h ? t0    : dw[0];
            paw[2 * kk][1]     = h ? t1    : dw[1];
            paw[2 * kk][2]     = h ? dw[2] : t0;
            paw[2 * kk][3]     = h ? dw[3] : t1;
            paw[2 * kk + 1][0] = h ? t2    : dw[4];
            paw[2 * kk + 1][1] = h ? t3    : dw[5];
            paw[2 * kk + 1][2] = h ? dw[6] : t2;
            paw[2 * kk + 1][3] = h ? dw[7] : t3;
        }

        // ---- ctx += P V ----
        __builtin_amdgcn_s_setprio(1);
        #pragma unroll
        for (int c = 0; c < 4; ++c) {
            PFrag pf;
            pf.u[0] = paw[c][0]; pf.u[1] = paw[c][1];
            pf.u[2] = paw[c][2]; pf.u[3] = paw[c][3];
            #pragma unroll
            for (int dt = 0; dt < 2; ++dt) {
                const f16x8 vb = *(const f16x8*)(Vp + (dt * 32 + l31) * 128
                                                    + ((c * 32 + h * 16) ^ sl));
                ctx[dt] = __builtin_amdgcn_mfma_f32_32x32x16_f16(pf.v, vb, ctx[dt], 0, 0, 0);
            }
        }
        __builtin_amdgcn_s_setprio(0);

        __syncthreads();
    }

    // ---- epilogue: write raw f16 partial + lsum (no normalization) ----
    {
        const float ltot = lsum + __shfl_xor(lsum, 32);   // per q = l31
        if (h == 0)
            L[(size_t)half * (NBH * SEQ) + bh * SEQ + q0 + w * 32 + l31] = ltot;
        f16* Od = half ? PB : PA;
        #pragma unroll
        for (int r = 0; r < 16; ++r) {
            const size_t row = rowbase + q0 + w * 32 + QMAP(r, h);
            Od[row * D_MODEL + qcol + l31]      = (f16)ctx[0][r];
            Od[row * D_MODEL + qcol + 32 + l31] = (f16)ctx[1][r];
        }
    }
}

// ---------------------------------------------------------------------------
// Merge halves: PB (=ctxh) <- (PA + PB) / (LA + LB), elementwise in-place.
// 786432 f16x8 chunks, grid 3072.
// ---------------------------------------------------------------------------
__global__ __launch_bounds__(256) void merge_halves(
    const f16* __restrict__ PA, f16* __restrict__ PB,
    const float* __restrict__ L)
{
    const int i   = blockIdx.x * 256 + threadIdx.x;   // f16x8 chunk index
    const int c8  = i % 96;                           // chunk within row
    const int row = i / 96;
    const int h   = c8 >> 3;
    const int b   = row >> 10;
    const int tok = row & 1023;
    const int bh  = b * NHEAD + h;
    const float la = L[bh * SEQ + tok];
    const float lb = L[NBH * SEQ + bh * SEQ + tok];
    const float inv = 1.0f / (la + lb);
    const f16x8 a = *(const f16x8*)(PA + (size_t)i * 8);
    const f16x8 c = *(const f16x8*)(PB + (size_t)i * 8);
    f16x8 o;
    #pragma unroll
    for (int j = 0; j < 8; ++j)
        o[j] = (f16)(((float)a[j] + (float)c[j]) * inv);
    *(f16x8*)(PB + (size_t)i * 8) = o;
}

// ---------------------------------------------------------------------------
extern "C" void kernel_launch(void* const* d_in, const int* in_sizes, int n_in,
                              void* d_out, int out_size, void* d_ws, size_t ws_size,
                              hipStream_t stream) {
    const float* x  = (const float*)d_in[0];
    const float* Wq = (const float*)d_in[1];
    const float* bq = (const float*)d_in[2];
    const float* Wk = (const float*)d_in[3];
    const float* bk = (const float*)d_in[4];
    const float* Wv = (const float*)d_in[5];
    const float* bv = (const float*)d_in[6];
    const float* Wo = (const float*)d_in[7];
    const float* bo = (const float*)d_in[8];
    float* out = (float*)d_out;

    char* ws = (char*)d_ws;
    f16*   QKb     = (f16*)(ws);                       // 25,165,824
    f16*   Vt      = (f16*)(ws + 25165824);            // 12,582,912
    f16*   xh      = (f16*)(ws + 37748736);            // 12,582,912 (-> PA after QKV gemm)
    f16*   ctxh    = (f16*)(ws + 50331648);            // 12,582,912 (= PB, merged in place)
    f16*   Wqkv_t  = (f16*)(ws + 62914560);            // 3,538,944  (-> L after QKV gemm)
    f16*   Wo_t    = (f16*)(ws + 66453504);            // 1,179,648
    float* bqkv    = (float*)(ws + 67633152);          // 9,216
    float* Lbuf    = (float*)Wqkv_t;                   // [2][96][1024] f32 = 786,432 B

    // merged prepass: 3072 cvt blocks + 576 transpose blocks
    hipLaunchKernelGGL(prepass, dim3(3648), dim3(256), 0, stream,
                       x, xh, MTOT * D_MODEL / 8, bq, bk, bv, bqkv,
                       Wq, Wk, Wv, Wo, Wqkv_t, Wo_t);

    // fused QKV projection: QK -> QKb (ld 1536), V -> Vt (transposed).
    hipLaunchKernelGGL((gemm_f16_tn<f16, true, 128>), dim3((QKV_N / 128) * (MTOT / 128)), dim3(256), 0, stream,
                       xh, Wqkv_t, bqkv, QKb, Vt, MTOT, QKV_N, D_MODEL, QKV_N / 128, QK_LD);

    // attention, kv-split across blocks: half0 partial -> xh, half1 -> ctxh
    hipLaunchKernelGGL(attn_f16, dim3(2 * (SEQ / 128) * NBH), dim3(256), 0, stream,
                       QKb, Vt, xh, ctxh, Lbuf);

    // merge partials (in place into ctxh)
    hipLaunchKernelGGL(merge_halves, dim3(MTOT * D_MODEL / 8 / 256), dim3(256), 0, stream,
                       xh, ctxh, Lbuf);

    // output projection: 128x64 tiles -> grid 12*64 = 768 = exactly 3/CU
    hipLaunchKernelGGL((gemm_f16_tn<float, false, 64>), dim3((D_MODEL / 64) * (MTOT / 128)), dim3(256), 0, stream,
                       ctxh, Wo_t, bo, out, (f16*)nullptr, MTOT, D_MODEL, D_MODEL, D_MODEL / 64, D_MODEL);
}

// Round 18
// 119.603 us; speedup vs baseline: 1.0467x; 1.0467x over previous
//
#include <hip/hip_runtime.h>
#include <math.h>

#define D_MODEL 768
#define NHEAD  12
#define HDIM   64
#define SEQ    1024
#define BATCH  8
#define MTOT   (BATCH*SEQ)   // 8192
#define QKV_N  2304          // gemm output columns (Q|K|V)
#define QK_LD  1536          // Q|K buffer row stride (V lives in Vt)

typedef _Float16 f16;
typedef __attribute__((ext_vector_type(2))) __fp16 fp16x2;
typedef __attribute__((ext_vector_type(4))) _Float16 f16x4;
typedef __attribute__((ext_vector_type(8))) _Float16 f16x8;
typedef __attribute__((ext_vector_type(4))) float f32x4;
typedef __attribute__((ext_vector_type(16))) float f32x16;

union PFrag { unsigned u[4]; f16x8 v; };
union PackW { fp16x2 h; unsigned u; };

__device__ inline void gload_lds16(const void* g, void* l) {
    __builtin_amdgcn_global_load_lds(
        (const __attribute__((address_space(1))) void*)g,
        (__attribute__((address_space(3))) void*)l, 16, 0, 0);
}

// ---------------------------------------------------------------------------
// Merged prepass: blocks [0,3072) = x fp32->f16 (+bias concat in blocks 0..8);
// blocks [3072,3648) = four W transposes (idx selects matrix + tile).
// ---------------------------------------------------------------------------
__global__ __launch_bounds__(256) void prepass(
    const float* __restrict__ x, f16* __restrict__ xh, int n8,
    const float* __restrict__ bq, const float* __restrict__ bk,
    const float* __restrict__ bv, float* __restrict__ bqkv,
    const float* __restrict__ Wq, const float* __restrict__ Wk,
    const float* __restrict__ Wv, const float* __restrict__ Wo,
    f16* __restrict__ Wqkv_t, f16* __restrict__ Wo_t)
{
    __shared__ f16 tile[64][72];
    const int t = threadIdx.x;

    if (blockIdx.x < 3072) {
        const int i = blockIdx.x * 256 + t;
        if (i < n8) {
            const float4 a = *(const float4*)(x + (size_t)i * 8);
            const float4 b = *(const float4*)(x + (size_t)i * 8 + 4);
            f16x8 v;
            v[0] = (f16)a.x; v[1] = (f16)a.y; v[2] = (f16)a.z; v[3] = (f16)a.w;
            v[4] = (f16)b.x; v[5] = (f16)b.y; v[6] = (f16)b.z; v[7] = (f16)b.w;
            *(f16x8*)(xh + (size_t)i * 8) = v;
        }
        if (i < QKV_N)
            bqkv[i] = (i < 768) ? bq[i] : (i < 1536) ? bk[i - 768] : bv[i - 1536];
    } else {
        const int idx = blockIdx.x - 3072;
        const int z   = idx / 144;
        const int rem = idx % 144;
        const int k0  = (rem / 12) * 64;
        const int n0  = (rem % 12) * 64;
        const float* src = (z == 0) ? Wq : (z == 1) ? Wk : (z == 2) ? Wv : Wo;
        f16* dst = (z < 3) ? (Wqkv_t + (size_t)z * 768 * 768) : Wo_t;

        {
            const int r  = t >> 4;
            const int c4 = (t & 15) * 4;
            #pragma unroll
            for (int u = 0; u < 4; ++u) {
                const int row = r + u * 16;
                const float4 a = *(const float4*)&src[(size_t)(k0 + row) * 768 + n0 + c4];
                tile[row][c4 + 0] = (f16)a.x;
                tile[row][c4 + 1] = (f16)a.y;
                tile[row][c4 + 2] = (f16)a.z;
                tile[row][c4 + 3] = (f16)a.w;
            }
        }
        __syncthreads();
        {
            const int rn = t >> 3;
            const int ck = (t & 7) * 8;
            #pragma unroll
            for (int u = 0; u < 2; ++u) {
                const int n = rn + u * 32;
                f16x8 v;
                #pragma unroll
                for (int q = 0; q < 8; ++q) v[q] = tile[ck + q][n];
                *(f16x8*)&dst[(size_t)(n0 + n) * 768 + k0 + ck] = v;
            }
        }
    }
}

// ---------------------------------------------------------------------------
// C[M][N] = A[M][K]f16 @ Bt[N][K]f16^T + bias.  128xBN tile, 4 waves,
// 64x(BN/2)/wave, BK=64. global_load_lds(16B) staging; 8-slot add-rotate
// k-chunk swizzle. 1D grid, XCD-contiguous chunk mapping.
// BN=128 for QKV (grid 1152); BN=64 for Wo (grid 768 = exactly 3/CU).
// SPLITV: cols >= 1536 (V) scatter to Vt[bh][d][seq] (transposed f16x4).
// ---------------------------------------------------------------------------
template<typename OUT_T, bool SPLITV, int BN>
__global__ __launch_bounds__(256) void gemm_f16_tn(
    const f16* __restrict__ A, const f16* __restrict__ Bt,
    const float* __restrict__ bias, OUT_T* __restrict__ C,
    f16* __restrict__ Vt,
    int M, int N, int K, int nb, int ldc)
{
    constexpr int NJ = BN / 32;          // j-tiles per wave (4 or 2)
    __shared__ f16 As[128 * 64];
    __shared__ f16 Bs[BN * 64];

    const int t    = threadIdx.x;
    const int l15  = (t & 63) & 15;
    const int lg   = (t & 63) >> 4;
    const int w    = t >> 6;
    const int wrow = (w >> 1) * 64;
    const int wcol = (w & 1) * (BN / 2);

    const int orig = blockIdx.x;
    const int cpx  = gridDim.x >> 3;
    const int nid  = (orig & 7) * cpx + (orig >> 3);
    const int row0 = (nid / nb) * 128;
    const int col0 = (nid % nb) * BN;

    int src_row[4], src_koff[4], lds_off[4];
    #pragma unroll
    for (int i = 0; i < 4; ++i) {
        const int c = t + 256 * i;
        const int r = c >> 3;
        src_row[i]  = r;
        src_koff[i] = ((((c & 7) - (r >> 1)) & 7)) * 8;
        lds_off[i]  = c * 16;
    }

    int a_off[4][2], b_off[NJ][2];
    #pragma unroll
    for (int i = 0; i < 4; ++i) {
        const int ra = wrow + i * 16 + l15;
        #pragma unroll
        for (int s = 0; s < 2; ++s)
            a_off[i][s] = ra * 128 + (((s * 4 + lg + (ra >> 1)) & 7) * 16);
    }
    #pragma unroll
    for (int j = 0; j < NJ; ++j) {
        const int rb = wcol + j * 16 + l15;
        #pragma unroll
        for (int s = 0; s < 2; ++s)
            b_off[j][s] = rb * 128 + (((s * 4 + lg + (rb >> 1)) & 7) * 16);
    }

    f32x4 acc[4][NJ];
    #pragma unroll
    for (int i = 0; i < 4; ++i)
        #pragma unroll
        for (int j = 0; j < NJ; ++j)
            acc[i][j] = (f32x4){0.f, 0.f, 0.f, 0.f};

    const f16* Abase = A  + (size_t)row0 * K;
    const f16* Bbase = Bt + (size_t)col0 * K;

    for (int k0 = 0; k0 < K; k0 += 64) {
        #pragma unroll
        for (int i = 0; i < 4; ++i)
            gload_lds16(Abase + (size_t)src_row[i] * K + k0 + src_koff[i],
                        (char*)As + lds_off[i]);
        #pragma unroll
        for (int i = 0; i < BN / 32; ++i)
            gload_lds16(Bbase + (size_t)src_row[i] * K + k0 + src_koff[i],
                        (char*)Bs + lds_off[i]);
        __syncthreads();

        #pragma unroll
        for (int s = 0; s < 2; ++s) {
            f16x8 af[4], bf[NJ];
            #pragma unroll
            for (int i = 0; i < 4; ++i)
                af[i] = *(const f16x8*)((const char*)As + a_off[i][s]);
            #pragma unroll
            for (int j = 0; j < NJ; ++j)
                bf[j] = *(const f16x8*)((const char*)Bs + b_off[j][s]);
            #pragma unroll
            for (int i = 0; i < 4; ++i)
                #pragma unroll
                for (int j = 0; j < NJ; ++j)
                    acc[i][j] = __builtin_amdgcn_mfma_f32_16x16x32_f16(
                        af[i], bf[j], acc[i][j], 0, 0, 0);
        }
        __syncthreads();
    }

    #pragma unroll
    for (int j = 0; j < NJ; ++j) {
        const int col = col0 + wcol + j * 16 + l15;
        const float bj = bias[col];
        if (!SPLITV || col < 1536) {
            #pragma unroll
            for (int i = 0; i < 4; ++i) {
                const int row = row0 + wrow + i * 16 + lg * 4;
                #pragma unroll
                for (int q = 0; q < 4; ++q)
                    C[(size_t)(row + q) * ldc + col] = (OUT_T)(acc[i][j][q] + bj);
            }
        } else if (SPLITV) {
            const int h2 = (col - 1536) >> 6;
            const int d  = (col - 1536) & 63;
            #pragma unroll
            for (int i = 0; i < 4; ++i) {
                const int row = row0 + wrow + i * 16 + lg * 4;
                const int bb  = row >> 10;
                const int tok = row & 1023;
                f16x4 v4;
                #pragma unroll
                for (int q = 0; q < 4; ++q) v4[q] = (f16)(acc[i][j][q] + bj);
                *(f16x4*)(Vt + (((size_t)(bb * NHEAD + h2)) * 64 + d) * SEQ + tok) = v4;
            }
        }
    }
}

// ---------------------------------------------------------------------------
// Flash attention, f16, 32x32x16 MFMA, fixed-shift softmax, ALL staging
// via global_load_lds with pre-swizzled sources (round-15/16 proven).
// QBLK=128 (32 q-rows/wave), KVB=64, swapped QK^T (lane-local q=l&31),
// P packed in-register (cvt_pkrtz + shfl_xor32), double-buffered,
// 1 barrier/kt. grid = 768 1D, XCD-contiguous. LDS 32KB.
// ---------------------------------------------------------------------------
#define QMAP(r, hh) (((r) & 3) + 8 * ((r) >> 2) + 4 * (hh))

__global__ __launch_bounds__(256, 3) void attn_f16(
    const f16* __restrict__ QK, const f16* __restrict__ Vt,
    f16* __restrict__ O)
{
    __shared__ f16 KsB[2][64 * 64];   // [k][d], swizzled
    __shared__ f16 VtB[2][64 * 64];   // [d][k], swizzled

    const int t   = threadIdx.x;
    const int w   = t >> 6;
    const int l   = t & 63;
    const int l31 = l & 31;
    const int h   = l >> 5;
    const int sl  = (l & 7) << 4;     // read XOR key (row&7)

    const int orig = blockIdx.x;                 // 0..767
    const int s    = (orig & 7) * 96 + (orig >> 3);
    const int bh   = s >> 3;                     // 0..95
    const int qb   = s & 7;                      // 0..7
    const int b  = bh / NHEAD;
    const int hd = bh % NHEAD;
    const int q0 = qb * 128;

    const size_t rowbase = (size_t)b * SEQ;
    const int qcol = hd * HDIM;

    // ---- hoist Q fragments (B-operand: col=l31=q, k=h*8+j per 16-d chunk) --
    const f16 hsc = (f16)(0.125f * 1.4426950408889634f);
    f16x8 qf[4];
    #pragma unroll
    for (int dc = 0; dc < 4; ++dc) {
        f16x8 v = *(const f16x8*)(QK
            + (rowbase + q0 + w * 32 + l31) * QK_LD
            + qcol + dc * 16 + h * 8);
        #pragma unroll
        for (int j = 0; j < 8; ++j) v[j] *= hsc;
        qf[dc] = v;
    }

    f32x16 ctx[2];
    #pragma unroll
    for (int dt = 0; dt < 2; ++dt)
        #pragma unroll
        for (int r = 0; r < 16; ++r) ctx[dt][r] = 0.f;
    float lsum = 0.f;   // per-lane partial P-sum (q = l31); reduced at end

    // ---- staging sources (pre-swizzled) ----
    const int rsub   = l >> 3;                 // row within 8-row call
    const int schunk = (l & 7) ^ rsub;         // source 16B-chunk
    const f16* ksrc = QK + (rowbase + w * 16 + rsub) * QK_LD
                         + 768 + qcol + schunk * 8;
    const f16* vsrc = Vt + (((size_t)bh * 64) + w * 16 + rsub) * SEQ
                         + schunk * 8;
    const size_t kstep = (size_t)64 * QK_LD;   // K rows advance per tile
    const int    woff  = w * 2048;             // wave's 16-row LDS chunk

    // ---- prologue: DMA tile 0 into buf 0 ----
    gload_lds16(ksrc,             (char*)KsB[0] + woff);
    gload_lds16(ksrc + 8 * QK_LD, (char*)KsB[0] + woff + 1024);
    gload_lds16(vsrc,             (char*)VtB[0] + woff);
    gload_lds16(vsrc + 8 * SEQ,   (char*)VtB[0] + woff + 1024);
    __syncthreads();

    for (int kt = 0; kt < SEQ / 64; ++kt) {
        const int p = kt & 1;

        // ---- DMA tile kt+1 into buf p^1 (drains by end-of-iter barrier) ----
        if (kt < SEQ / 64 - 1) {
            const f16* ks = ksrc + (size_t)(kt + 1) * kstep;
            const f16* vs = vsrc + (kt + 1) * 64;
            gload_lds16(ks,             (char*)KsB[p ^ 1] + woff);
            gload_lds16(ks + 8 * QK_LD, (char*)KsB[p ^ 1] + woff + 1024);
            gload_lds16(vs,             (char*)VtB[p ^ 1] + woff);
            gload_lds16(vs + 8 * SEQ,   (char*)VtB[p ^ 1] + woff + 1024);
        }

        const char* Kp = (const char*)KsB[p];
        const char* Vp = (const char*)VtB[p];

        // ---- S^T = K @ Q^T : 2 k-tiles of 32x32, contraction d=64 ----
        f32x16 sacc[2];
        __builtin_amdgcn_s_setprio(1);
        #pragma unroll
        for (int kk = 0; kk < 2; ++kk) {
            f32x16 a;
            #pragma unroll
            for (int r = 0; r < 16; ++r) a[r] = 0.f;
            #pragma unroll
            for (int dc = 0; dc < 4; ++dc) {
                const f16x8 ka = *(const f16x8*)(Kp + (kk * 32 + l31) * 128
                                                    + ((dc * 32 + h * 16) ^ sl));
                a = __builtin_amdgcn_mfma_f32_32x32x16_f16(ka, qf[dc], a, 0, 0, 0);
            }
            sacc[kk] = a;
        }
        __builtin_amdgcn_s_setprio(0);

        // ---- fixed-shift softmax: P = exp2(s), 4-way tree partial sum ----
        {
            float ps0 = 0.f, ps1 = 0.f, ps2 = 0.f, ps3 = 0.f;
            #pragma unroll
            for (int kk = 0; kk < 2; ++kk)
                #pragma unroll
                for (int r = 0; r < 16; r += 4) {
                    const float e0 = exp2f(sacc[kk][r + 0]);
                    const float e1 = exp2f(sacc[kk][r + 1]);
                    const float e2 = exp2f(sacc[kk][r + 2]);
                    const float e3 = exp2f(sacc[kk][r + 3]);
                    sacc[kk][r + 0] = e0; ps0 += e0;
                    sacc[kk][r + 1] = e1; ps1 += e1;
                    sacc[kk][r + 2] = e2; ps2 += e2;
                    sacc[kk][r + 3] = e3; ps3 += e3;
                }
            lsum += (ps0 + ps1) + (ps2 + ps3);
        }

        // ---- pack P to f16 dwords, redistribute across half-waves ----
        unsigned paw[4][4];
        #pragma unroll
        for (int kk = 0; kk < 2; ++kk) {
            unsigned dw[8];
            #pragma unroll
            for (int i = 0; i < 8; ++i) {
                PackW u;
                u.h = __builtin_amdgcn_cvt_pkrtz(sacc[kk][2 * i], sacc[kk][2 * i + 1]);
                dw[i] = u.u;
            }
            const unsigned t0 = (unsigned)__shfl_xor((int)(h ? dw[0] : dw[2]), 32);
            const unsigned t1 = (unsigned)__shfl_xor((int)(h ? dw[1] : dw[3]), 32);
            const unsigned t2 = (unsigned)__shfl_xor((int)(h ? dw[4] : dw[6]), 32);
            const unsigned t3 = (unsigned)__shfl_xor((int)(h ? dw[5] : dw[7]), 32);
            paw[2 * kk][0]     = h ? t0    : dw[0];
            paw[2 * kk][1]     = h ? t1    : dw[1];
            paw[2 * kk][2]     = h ? dw[2] : t0;
            paw[2 * kk][3]     = h ? dw[3] : t1;
            paw[2 * kk + 1][0] = h ? t2    : dw[4];
            paw[2 * kk + 1][1] = h ? t3    : dw[5];
            paw[2 * kk + 1][2] = h ? dw[6] : t2;
            paw[2 * kk + 1][3] = h ? dw[7] : t3;
        }

        // ---- ctx += P V : A in-register, B = Vt swizzled b128 ----
        __builtin_amdgcn_s_setprio(1);
        #pragma unroll
        for (int c = 0; c < 4; ++c) {
            PFrag pf;
            pf.u[0] = paw[c][0]; pf.u[1] = paw[c][1];
            pf.u[2] = paw[c][2]; pf.u[3] = paw[c][3];
            #pragma unroll
            for (int dt = 0; dt < 2; ++dt) {
                const f16x8 vb = *(const f16x8*)(Vp + (dt * 32 + l31) * 128
                                                    + ((c * 32 + h * 16) ^ sl));
                ctx[dt] = __builtin_amdgcn_mfma_f32_32x32x16_f16(pf.v, vb, ctx[dt], 0, 0, 0);
            }
        }
        __builtin_amdgcn_s_setprio(0);

        __syncthreads();   // readers done with buf p; DMA for p^1 drained
    }

    // ---- final l reduce + normalize + store ----
    {
        const float ltot = lsum + __shfl_xor(lsum, 32);   // q = l31
        const float inv  = 1.0f / ltot;
        #pragma unroll
        for (int r = 0; r < 16; ++r) {
            const float iv = __shfl(inv, QMAP(r, h));
            const size_t row = rowbase + q0 + w * 32 + QMAP(r, h);
            O[row * D_MODEL + qcol + l31]      = (f16)(ctx[0][r] * iv);
            O[row * D_MODEL + qcol + 32 + l31] = (f16)(ctx[1][r] * iv);
        }
    }
}

// ---------------------------------------------------------------------------
extern "C" void kernel_launch(void* const* d_in, const int* in_sizes, int n_in,
                              void* d_out, int out_size, void* d_ws, size_t ws_size,
                              hipStream_t stream) {
    const float* x  = (const float*)d_in[0];
    const float* Wq = (const float*)d_in[1];
    const float* bq = (const float*)d_in[2];
    const float* Wk = (const float*)d_in[3];
    const float* bk = (const float*)d_in[4];
    const float* Wv = (const float*)d_in[5];
    const float* bv = (const float*)d_in[6];
    const float* Wo = (const float*)d_in[7];
    const float* bo = (const float*)d_in[8];
    float* out = (float*)d_out;

    char* ws = (char*)d_ws;
    f16*   QKb     = (f16*)(ws);                       // 25,165,824
    f16*   Vt      = (f16*)(ws + 25165824);            // 12,582,912
    f16*   xh      = (f16*)(ws + 37748736);            // 12,582,912
    f16*   ctxh    = (f16*)(ws + 50331648);            // 12,582,912
    f16*   Wqkv_t  = (f16*)(ws + 62914560);            // 3,538,944
    f16*   Wo_t    = (f16*)(ws + 66453504);            // 1,179,648
    float* bqkv    = (float*)(ws + 67633152);          // 9,216

    // merged prepass: 3072 cvt blocks + 576 transpose blocks
    hipLaunchKernelGGL(prepass, dim3(3648), dim3(256), 0, stream,
                       x, xh, MTOT * D_MODEL / 8, bq, bk, bv, bqkv,
                       Wq, Wk, Wv, Wo, Wqkv_t, Wo_t);

    // fused QKV projection: QK -> QKb (ld 1536), V -> Vt (transposed).
    hipLaunchKernelGGL((gemm_f16_tn<f16, true, 128>), dim3((QKV_N / 128) * (MTOT / 128)), dim3(256), 0, stream,
                       xh, Wqkv_t, bqkv, QKb, Vt, MTOT, QKV_N, D_MODEL, QKV_N / 128, QK_LD);

    hipLaunchKernelGGL(attn_f16, dim3((SEQ / 128) * BATCH * NHEAD), dim3(256), 0, stream,
                       QKb, Vt, ctxh);

    // output projection: 128x64 tiles -> grid 12*64 = 768 = exactly 3/CU
    hipLaunchKernelGGL((gemm_f16_tn<float, false, 64>), dim3((D_MODEL / 64) * (MTOT / 128)), dim3(256), 0, stream,
                       ctxh, Wo_t, bo, out, (f16*)nullptr, MTOT, D_MODEL, D_MODEL, D_MODEL / 64, D_MODEL);
}

// Round 19
// 119.096 us; speedup vs baseline: 1.0511x; 1.0043x over previous
//
#include <hip/hip_runtime.h>
#include <math.h>

#define D_MODEL 768
#define NHEAD  12
#define HDIM   64
#define SEQ    1024
#define BATCH  8
#define MTOT   (BATCH*SEQ)   // 8192
#define QKV_N  2304          // gemm output columns (Q|K|V)
#define QK_LD  1536          // Q|K buffer row stride (V lives in Vt)

typedef _Float16 f16;
typedef __attribute__((ext_vector_type(2))) __fp16 fp16x2;
typedef __attribute__((ext_vector_type(4))) _Float16 f16x4;
typedef __attribute__((ext_vector_type(8))) _Float16 f16x8;
typedef __attribute__((ext_vector_type(4))) float f32x4;
typedef __attribute__((ext_vector_type(16))) float f32x16;

union PFrag { unsigned u[4]; f16x8 v; };
union PackW { fp16x2 h; unsigned u; };

__device__ inline void gload_lds16(const void* g, void* l) {
    __builtin_amdgcn_global_load_lds(
        (const __attribute__((address_space(1))) void*)g,
        (__attribute__((address_space(3))) void*)l, 16, 0, 0);
}

// ---------------------------------------------------------------------------
// Merged prepass: blocks [0,3072) = x fp32->f16 (+bias concat in blocks 0..8);
// blocks [3072,3648) = four W transposes (idx selects matrix + tile).
// ---------------------------------------------------------------------------
__global__ __launch_bounds__(256) void prepass(
    const float* __restrict__ x, f16* __restrict__ xh, int n8,
    const float* __restrict__ bq, const float* __restrict__ bk,
    const float* __restrict__ bv, float* __restrict__ bqkv,
    const float* __restrict__ Wq, const float* __restrict__ Wk,
    const float* __restrict__ Wv, const float* __restrict__ Wo,
    f16* __restrict__ Wqkv_t, f16* __restrict__ Wo_t)
{
    __shared__ f16 tile[64][72];
    const int t = threadIdx.x;

    if (blockIdx.x < 3072) {
        const int i = blockIdx.x * 256 + t;
        if (i < n8) {
            const float4 a = *(const float4*)(x + (size_t)i * 8);
            const float4 b = *(const float4*)(x + (size_t)i * 8 + 4);
            f16x8 v;
            v[0] = (f16)a.x; v[1] = (f16)a.y; v[2] = (f16)a.z; v[3] = (f16)a.w;
            v[4] = (f16)b.x; v[5] = (f16)b.y; v[6] = (f16)b.z; v[7] = (f16)b.w;
            *(f16x8*)(xh + (size_t)i * 8) = v;
        }
        if (i < QKV_N)
            bqkv[i] = (i < 768) ? bq[i] : (i < 1536) ? bk[i - 768] : bv[i - 1536];
    } else {
        const int idx = blockIdx.x - 3072;
        const int z   = idx / 144;
        const int rem = idx % 144;
        const int k0  = (rem / 12) * 64;
        const int n0  = (rem % 12) * 64;
        const float* src = (z == 0) ? Wq : (z == 1) ? Wk : (z == 2) ? Wv : Wo;
        f16* dst = (z < 3) ? (Wqkv_t + (size_t)z * 768 * 768) : Wo_t;

        {
            const int r  = t >> 4;
            const int c4 = (t & 15) * 4;
            #pragma unroll
            for (int u = 0; u < 4; ++u) {
                const int row = r + u * 16;
                const float4 a = *(const float4*)&src[(size_t)(k0 + row) * 768 + n0 + c4];
                tile[row][c4 + 0] = (f16)a.x;
                tile[row][c4 + 1] = (f16)a.y;
                tile[row][c4 + 2] = (f16)a.z;
                tile[row][c4 + 3] = (f16)a.w;
            }
        }
        __syncthreads();
        {
            const int rn = t >> 3;
            const int ck = (t & 7) * 8;
            #pragma unroll
            for (int u = 0; u < 2; ++u) {
                const int n = rn + u * 32;
                f16x8 v;
                #pragma unroll
                for (int q = 0; q < 8; ++q) v[q] = tile[ck + q][n];
                *(f16x8*)&dst[(size_t)(n0 + n) * 768 + k0 + ck] = v;
            }
        }
    }
}

// ---------------------------------------------------------------------------
// C[M][N] = A[M][K]f16 @ Bt[N][K]f16^T + bias.  128xBN tile, 4 waves,
// 64x(BN/2)/wave, BK=64. global_load_lds(16B) staging; 8-slot add-rotate
// k-chunk swizzle. 1D grid, XCD-contiguous chunk mapping.
// BN=128 for QKV (grid 1152); BN=64 for Wo (grid 768 = exactly 3/CU).
// SPLITV: cols >= 1536 (V) scatter to Vt[bh][d][seq] (transposed f16x4).
// ---------------------------------------------------------------------------
template<typename OUT_T, bool SPLITV, int BN>
__global__ __launch_bounds__(256) void gemm_f16_tn(
    const f16* __restrict__ A, const f16* __restrict__ Bt,
    const float* __restrict__ bias, OUT_T* __restrict__ C,
    f16* __restrict__ Vt,
    int M, int N, int K, int nb, int ldc)
{
    constexpr int NJ = BN / 32;          // j-tiles per wave (4 or 2)
    __shared__ f16 As[128 * 64];
    __shared__ f16 Bs[BN * 64];

    const int t    = threadIdx.x;
    const int l15  = (t & 63) & 15;
    const int lg   = (t & 63) >> 4;
    const int w    = t >> 6;
    const int wrow = (w >> 1) * 64;
    const int wcol = (w & 1) * (BN / 2);

    const int orig = blockIdx.x;
    const int cpx  = gridDim.x >> 3;
    const int nid  = (orig & 7) * cpx + (orig >> 3);
    const int row0 = (nid / nb) * 128;
    const int col0 = (nid % nb) * BN;

    int src_row[4], src_koff[4], lds_off[4];
    #pragma unroll
    for (int i = 0; i < 4; ++i) {
        const int c = t + 256 * i;
        const int r = c >> 3;
        src_row[i]  = r;
        src_koff[i] = ((((c & 7) - (r >> 1)) & 7)) * 8;
        lds_off[i]  = c * 16;
    }

    int a_off[4][2], b_off[NJ][2];
    #pragma unroll
    for (int i = 0; i < 4; ++i) {
        const int ra = wrow + i * 16 + l15;
        #pragma unroll
        for (int s = 0; s < 2; ++s)
            a_off[i][s] = ra * 128 + (((s * 4 + lg + (ra >> 1)) & 7) * 16);
    }
    #pragma unroll
    for (int j = 0; j < NJ; ++j) {
        const int rb = wcol + j * 16 + l15;
        #pragma unroll
        for (int s = 0; s < 2; ++s)
            b_off[j][s] = rb * 128 + (((s * 4 + lg + (rb >> 1)) & 7) * 16);
    }

    f32x4 acc[4][NJ];
    #pragma unroll
    for (int i = 0; i < 4; ++i)
        #pragma unroll
        for (int j = 0; j < NJ; ++j)
            acc[i][j] = (f32x4){0.f, 0.f, 0.f, 0.f};

    const f16* Abase = A  + (size_t)row0 * K;
    const f16* Bbase = Bt + (size_t)col0 * K;

    for (int k0 = 0; k0 < K; k0 += 64) {
        #pragma unroll
        for (int i = 0; i < 4; ++i)
            gload_lds16(Abase + (size_t)src_row[i] * K + k0 + src_koff[i],
                        (char*)As + lds_off[i]);
        #pragma unroll
        for (int i = 0; i < BN / 32; ++i)
            gload_lds16(Bbase + (size_t)src_row[i] * K + k0 + src_koff[i],
                        (char*)Bs + lds_off[i]);
        __syncthreads();

        #pragma unroll
        for (int s = 0; s < 2; ++s) {
            f16x8 af[4], bf[NJ];
            #pragma unroll
            for (int i = 0; i < 4; ++i)
                af[i] = *(const f16x8*)((const char*)As + a_off[i][s]);
            #pragma unroll
            for (int j = 0; j < NJ; ++j)
                bf[j] = *(const f16x8*)((const char*)Bs + b_off[j][s]);
            #pragma unroll
            for (int i = 0; i < 4; ++i)
                #pragma unroll
                for (int j = 0; j < NJ; ++j)
                    acc[i][j] = __builtin_amdgcn_mfma_f32_16x16x32_f16(
                        af[i], bf[j], acc[i][j], 0, 0, 0);
        }
        __syncthreads();
    }

    #pragma unroll
    for (int j = 0; j < NJ; ++j) {
        const int col = col0 + wcol + j * 16 + l15;
        const float bj = bias[col];
        if (!SPLITV || col < 1536) {
            #pragma unroll
            for (int i = 0; i < 4; ++i) {
                const int row = row0 + wrow + i * 16 + lg * 4;
                #pragma unroll
                for (int q = 0; q < 4; ++q)
                    C[(size_t)(row + q) * ldc + col] = (OUT_T)(acc[i][j][q] + bj);
            }
        } else if (SPLITV) {
            const int h2 = (col - 1536) >> 6;
            const int d  = (col - 1536) & 63;
            #pragma unroll
            for (int i = 0; i < 4; ++i) {
                const int row = row0 + wrow + i * 16 + lg * 4;
                const int bb  = row >> 10;
                const int tok = row & 1023;
                f16x4 v4;
                #pragma unroll
                for (int q = 0; q < 4; ++q) v4[q] = (f16)(acc[i][j][q] + bj);
                *(f16x4*)(Vt + (((size_t)(bb * NHEAD + h2)) * 64 + d) * SEQ + tok) = v4;
            }
        }
    }
}

// ---------------------------------------------------------------------------
// Flash attention, f16, 32x32x16 MFMA, fixed-shift softmax, DMA staging
// with pre-swizzled sources — now 3-DEEP PIPELINE + COUNTED VMCNT (T4):
// per iter: issue DMA(kt+2) -> compute buf kt%3 -> s_waitcnt vmcnt(4)
// (confirms DMA(kt+1); kt+2's 4 loads stay in flight ACROSS the barrier)
// -> raw s_barrier. Never vmcnt(0) in the main loop. 48KB LDS = 3 buf
// pairs -> still 3 blocks/CU. QBLK=128 (32 q-rows/wave), KVB=64,
// swapped QK^T (lane-local q=l&31), P packed in-register.
// grid = 768 1D, XCD-contiguous.
// ---------------------------------------------------------------------------
#define QMAP(r, hh) (((r) & 3) + 8 * ((r) >> 2) + 4 * (hh))

__global__ __launch_bounds__(256, 3) void attn_f16(
    const f16* __restrict__ QK, const f16* __restrict__ Vt,
    f16* __restrict__ O)
{
    __shared__ f16 KsB[3][64 * 64];   // [k][d], swizzled
    __shared__ f16 VtB[3][64 * 64];   // [d][k], swizzled

    const int t   = threadIdx.x;
    const int w   = t >> 6;
    const int l   = t & 63;
    const int l31 = l & 31;
    const int h   = l >> 5;
    const int sl  = (l & 7) << 4;     // read XOR key (row&7)

    const int orig = blockIdx.x;                 // 0..767
    const int s    = (orig & 7) * 96 + (orig >> 3);
    const int bh   = s >> 3;                     // 0..95
    const int qb   = s & 7;                      // 0..7
    const int b  = bh / NHEAD;
    const int hd = bh % NHEAD;
    const int q0 = qb * 128;

    const size_t rowbase = (size_t)b * SEQ;
    const int qcol = hd * HDIM;

    // ---- hoist Q fragments (B-operand: col=l31=q, k=h*8+j per 16-d chunk) --
    const f16 hsc = (f16)(0.125f * 1.4426950408889634f);
    f16x8 qf[4];
    #pragma unroll
    for (int dc = 0; dc < 4; ++dc) {
        f16x8 v = *(const f16x8*)(QK
            + (rowbase + q0 + w * 32 + l31) * QK_LD
            + qcol + dc * 16 + h * 8);
        #pragma unroll
        for (int j = 0; j < 8; ++j) v[j] *= hsc;
        qf[dc] = v;
    }

    f32x16 ctx[2];
    #pragma unroll
    for (int dt = 0; dt < 2; ++dt)
        #pragma unroll
        for (int r = 0; r < 16; ++r) ctx[dt][r] = 0.f;
    float lsum = 0.f;   // per-lane partial P-sum (q = l31); reduced at end

    // ---- staging sources (pre-swizzled) ----
    const int rsub   = l >> 3;                 // row within 8-row call
    const int schunk = (l & 7) ^ rsub;         // source 16B-chunk
    const f16* ksrc = QK + (rowbase + w * 16 + rsub) * QK_LD
                         + 768 + qcol + schunk * 8;
    const f16* vsrc = Vt + (((size_t)bh * 64) + w * 16 + rsub) * SEQ
                         + schunk * 8;
    const size_t kstep = (size_t)64 * QK_LD;   // K rows advance per tile
    const int    woff  = w * 2048;             // wave's 16-row LDS chunk

    // ---- prologue: DMA tiles 0,1 into bufs 0,1; wait tile 0 only ----
    gload_lds16(ksrc,                     (char*)KsB[0] + woff);
    gload_lds16(ksrc + 8 * QK_LD,         (char*)KsB[0] + woff + 1024);
    gload_lds16(vsrc,                     (char*)VtB[0] + woff);
    gload_lds16(vsrc + 8 * SEQ,           (char*)VtB[0] + woff + 1024);
    gload_lds16(ksrc + kstep,             (char*)KsB[1] + woff);
    gload_lds16(ksrc + kstep + 8 * QK_LD, (char*)KsB[1] + woff + 1024);
    gload_lds16(vsrc + 64,                (char*)VtB[1] + woff);
    gload_lds16(vsrc + 64 + 8 * SEQ,      (char*)VtB[1] + woff + 1024);
    asm volatile("s_waitcnt vmcnt(4)" ::: "memory");
    __builtin_amdgcn_sched_barrier(0);
    __builtin_amdgcn_s_barrier();

    for (int kt = 0; kt < SEQ / 64; ++kt) {
        const int p = kt % 3;

        // ---- issue DMA tile kt+2 into buf (kt+2)%3 (in flight 2 iters) ----
        if (kt < SEQ / 64 - 2) {
            const int pn = (kt + 2) % 3;
            const f16* ks = ksrc + (size_t)(kt + 2) * kstep;
            const f16* vs = vsrc + (kt + 2) * 64;
            gload_lds16(ks,             (char*)KsB[pn] + woff);
            gload_lds16(ks + 8 * QK_LD, (char*)KsB[pn] + woff + 1024);
            gload_lds16(vs,             (char*)VtB[pn] + woff);
            gload_lds16(vs + 8 * SEQ,   (char*)VtB[pn] + woff + 1024);
        }

        const char* Kp = (const char*)KsB[p];
        const char* Vp = (const char*)VtB[p];

        // ---- S^T = K @ Q^T : 2 k-tiles of 32x32, contraction d=64 ----
        f32x16 sacc[2];
        __builtin_amdgcn_s_setprio(1);
        #pragma unroll
        for (int kk = 0; kk < 2; ++kk) {
            f32x16 a;
            #pragma unroll
            for (int r = 0; r < 16; ++r) a[r] = 0.f;
            #pragma unroll
            for (int dc = 0; dc < 4; ++dc) {
                const f16x8 ka = *(const f16x8*)(Kp + (kk * 32 + l31) * 128
                                                    + ((dc * 32 + h * 16) ^ sl));
                a = __builtin_amdgcn_mfma_f32_32x32x16_f16(ka, qf[dc], a, 0, 0, 0);
            }
            sacc[kk] = a;
        }
        __builtin_amdgcn_s_setprio(0);

        // ---- fixed-shift softmax: P = exp2(s), 4-way tree partial sum ----
        {
            float ps0 = 0.f, ps1 = 0.f, ps2 = 0.f, ps3 = 0.f;
            #pragma unroll
            for (int kk = 0; kk < 2; ++kk)
                #pragma unroll
                for (int r = 0; r < 16; r += 4) {
                    const float e0 = exp2f(sacc[kk][r + 0]);
                    const float e1 = exp2f(sacc[kk][r + 1]);
                    const float e2 = exp2f(sacc[kk][r + 2]);
                    const float e3 = exp2f(sacc[kk][r + 3]);
                    sacc[kk][r + 0] = e0; ps0 += e0;
                    sacc[kk][r + 1] = e1; ps1 += e1;
                    sacc[kk][r + 2] = e2; ps2 += e2;
                    sacc[kk][r + 3] = e3; ps3 += e3;
                }
            lsum += (ps0 + ps1) + (ps2 + ps3);
        }

        // ---- pack P to f16 dwords, redistribute across half-waves ----
        unsigned paw[4][4];
        #pragma unroll
        for (int kk = 0; kk < 2; ++kk) {
            unsigned dw[8];
            #pragma unroll
            for (int i = 0; i < 8; ++i) {
                PackW u;
                u.h = __builtin_amdgcn_cvt_pkrtz(sacc[kk][2 * i], sacc[kk][2 * i + 1]);
                dw[i] = u.u;
            }
            const unsigned t0 = (unsigned)__shfl_xor((int)(h ? dw[0] : dw[2]), 32);
            const unsigned t1 = (unsigned)__shfl_xor((int)(h ? dw[1] : dw[3]), 32);
            const unsigned t2 = (unsigned)__shfl_xor((int)(h ? dw[4] : dw[6]), 32);
            const unsigned t3 = (unsigned)__shfl_xor((int)(h ? dw[5] : dw[7]), 32);
            paw[2 * kk][0]     = h ? t0    : dw[0];
            paw[2 * kk][1]     = h ? t1    : dw[1];
            paw[2 * kk][2]     = h ? dw[2] : t0;
            paw[2 * kk][3]     = h ? dw[3] : t1;
            paw[2 * kk + 1][0] = h ? t2    : dw[4];
            paw[2 * kk + 1][1] = h ? t3    : dw[5];
            paw[2 * kk + 1][2] = h ? dw[6] : t2;
            paw[2 * kk + 1][3] = h ? dw[7] : t3;
        }

        // ---- ctx += P V : A in-register, B = Vt swizzled b128 ----
        __builtin_amdgcn_s_setprio(1);
        #pragma unroll
        for (int c = 0; c < 4; ++c) {
            PFrag pf;
            pf.u[0] = paw[c][0]; pf.u[1] = paw[c][1];
            pf.u[2] = paw[c][2]; pf.u[3] = paw[c][3];
            #pragma unroll
            for (int dt = 0; dt < 2; ++dt) {
                const f16x8 vb = *(const f16x8*)(Vp + (dt * 32 + l31) * 128
                                                    + ((c * 32 + h * 16) ^ sl));
                ctx[dt] = __builtin_amdgcn_mfma_f32_32x32x16_f16(pf.v, vb, ctx[dt], 0, 0, 0);
            }
        }
        __builtin_amdgcn_s_setprio(0);

        // ---- counted wait: confirm tile kt+1 landed; kt+2 stays in flight --
        if (kt < SEQ / 64 - 2) {
            asm volatile("s_waitcnt vmcnt(4)" ::: "memory");
            __builtin_amdgcn_sched_barrier(0);
            __builtin_amdgcn_s_barrier();
        } else if (kt == SEQ / 64 - 2) {
            asm volatile("s_waitcnt vmcnt(0)" ::: "memory");
            __builtin_amdgcn_sched_barrier(0);
            __builtin_amdgcn_s_barrier();
        }
    }

    // ---- final l reduce + normalize + store ----
    {
        const float ltot = lsum + __shfl_xor(lsum, 32);   // q = l31
        const float inv  = 1.0f / ltot;
        #pragma unroll
        for (int r = 0; r < 16; ++r) {
            const float iv = __shfl(inv, QMAP(r, h));
            const size_t row = rowbase + q0 + w * 32 + QMAP(r, h);
            O[row * D_MODEL + qcol + l31]      = (f16)(ctx[0][r] * iv);
            O[row * D_MODEL + qcol + 32 + l31] = (f16)(ctx[1][r] * iv);
        }
    }
}

// ---------------------------------------------------------------------------
extern "C" void kernel_launch(void* const* d_in, const int* in_sizes, int n_in,
                              void* d_out, int out_size, void* d_ws, size_t ws_size,
                              hipStream_t stream) {
    const float* x  = (const float*)d_in[0];
    const float* Wq = (const float*)d_in[1];
    const float* bq = (const float*)d_in[2];
    const float* Wk = (const float*)d_in[3];
    const float* bk = (const float*)d_in[4];
    const float* Wv = (const float*)d_in[5];
    const float* bv = (const float*)d_in[6];
    const float* Wo = (const float*)d_in[7];
    const float* bo = (const float*)d_in[8];
    float* out = (float*)d_out;

    char* ws = (char*)d_ws;
    f16*   QKb     = (f16*)(ws);                       // 25,165,824
    f16*   Vt      = (f16*)(ws + 25165824);            // 12,582,912
    f16*   xh      = (f16*)(ws + 37748736);            // 12,582,912
    f16*   ctxh    = (f16*)(ws + 50331648);            // 12,582,912
    f16*   Wqkv_t  = (f16*)(ws + 62914560);            // 3,538,944
    f16*   Wo_t    = (f16*)(ws + 66453504);            // 1,179,648
    float* bqkv    = (float*)(ws + 67633152);          // 9,216

    // merged prepass: 3072 cvt blocks + 576 transpose blocks
    hipLaunchKernelGGL(prepass, dim3(3648), dim3(256), 0, stream,
                       x, xh, MTOT * D_MODEL / 8, bq, bk, bv, bqkv,
                       Wq, Wk, Wv, Wo, Wqkv_t, Wo_t);

    // fused QKV projection: QK -> QKb (ld 1536), V -> Vt (transposed).
    hipLaunchKernelGGL((gemm_f16_tn<f16, true, 128>), dim3((QKV_N / 128) * (MTOT / 128)), dim3(256), 0, stream,
                       xh, Wqkv_t, bqkv, QKb, Vt, MTOT, QKV_N, D_MODEL, QKV_N / 128, QK_LD);

    hipLaunchKernelGGL(attn_f16, dim3((SEQ / 128) * BATCH * NHEAD), dim3(256), 0, stream,
                       QKb, Vt, ctxh);

    // output projection: 128x64 tiles -> grid 12*64 = 768 = exactly 3/CU
    hipLaunchKernelGGL((gemm_f16_tn<float, false, 64>), dim3((D_MODEL / 64) * (MTOT / 128)), dim3(256), 0, stream,
                       ctxh, Wo_t, bo, out, (f16*)nullptr, MTOT, D_MODEL, D_MODEL, D_MODEL / 64, D_MODEL);
}